// Round 1
// baseline (250.807 us; speedup 1.0000x reference)
//
#include <hip/hip_runtime.h>

typedef unsigned short u16;
typedef unsigned int   u32;
typedef __attribute__((ext_vector_type(8))) short bf16x8;
typedef __attribute__((ext_vector_type(4))) float f32x4;

#define NB   16
#define NPTS 4096
#define SPTS 1024
#define BNT  65536   // NB*NPTS

__device__ __forceinline__ float bf2f(u16 u){ return __uint_as_float(((u32)u)<<16); }
__device__ __forceinline__ u16 f2bf(float f){
  u32 u = __float_as_uint(f);
  return (u16)((u + 0x7FFFu + ((u>>16)&1u))>>16);
}

// ---------------- W fp32 -> bf16 ----------------
__global__ __launch_bounds__(256) void convw_k(const float* __restrict__ w1, const float* __restrict__ w2,
                                               u16* __restrict__ w1b, u16* __restrict__ w2b){
  int i = blockIdx.x*256 + threadIdx.x;           // 131072 total
  if (i < 98304) w1b[i] = f2bf(w1[i]);
  else { int j = i - 98304; w2b[j] = f2bf(w2[j]); }
}

// ---------------- (B,C,S) fp32 -> rows (b*S+s)*ostride + c, bf16 ----------------
__global__ __launch_bounds__(256) void transpose_k(const float* __restrict__ in, u16* __restrict__ out,
                                                   int C, int S, int ostride){
  __shared__ float tl[64][65];
  int t = threadIdx.x;
  int b = blockIdx.y;
  int s0 = blockIdx.x * 64;
  for (int ct = 0; ct < C; ct += 64){
    __syncthreads();
    for (int i = t; i < 4096; i += 256){
      int sl = i & 63, cl = i >> 6;
      tl[sl][cl] = in[((size_t)b*C + ct + cl)*S + s0 + sl];
    }
    __syncthreads();
    for (int i = t; i < 4096; i += 256){
      int cl = i & 63, sl = i >> 6;
      out[((size_t)b*S + s0 + sl)*ostride + ct + cl] = f2bf(tl[sl][cl]);
    }
  }
}

// ---------------- 3-NN search + weighted feature interp -> X cols [128,384) ----------------
__global__ __launch_bounds__(128) void knn_k(const float* __restrict__ xyz1, const float* __restrict__ xyz2,
                                             const u16* __restrict__ p2t, u16* __restrict__ X){
  __shared__ float4 sxyz[SPTS];
  __shared__ float  swts[128][3];
  __shared__ int    sidx[128][3];
  int t  = threadIdx.x;
  int b  = blockIdx.x >> 5;
  int n0 = (blockIdx.x & 31) << 7;
  const float* x2b = xyz2 + (size_t)b*3*SPTS;
  for (int s = t; s < SPTS; s += 128)
    sxyz[s] = make_float4(x2b[s], x2b[SPTS+s], x2b[2*SPTS+s], 0.f);
  const float* x1b = xyz1 + (size_t)b*3*NPTS;
  int n = n0 + t;
  float qx = x1b[n], qy = x1b[NPTS+n], qz = x1b[2*NPTS+n];
  __syncthreads();

  float d0=3.4e38f, d1=3.4e38f, d2=3.4e38f;
  int   i0=0, i1=0, i2=0;
  for (int s = 0; s < SPTS; ++s){
    float4 p = sxyz[s];
    float dist;
    {
      #pragma clang fp contract(off)
      float dx = qx - p.x, dy = qy - p.y, dz = qz - p.z;
      dist = ((dx*dx) + (dy*dy)) + (dz*dz);   // match numpy rounding exactly (no fma)
    }
    if (dist < d2){
      bool c1 = dist < d1, c0 = dist < d0;
      d2 = c1 ? d1 : dist;                 i2 = c1 ? i1 : s;
      float nd1 = c1 ? (c0 ? d0 : dist) : d1;
      int   ni1 = c1 ? (c0 ? i0 : s)    : i1;
      d0 = c0 ? dist : d0;                 i0 = c0 ? s : i0;
      d1 = nd1;                            i1 = ni1;
    }
  }
  float r0 = 1.f/(d0 + 1e-8f), r1 = 1.f/(d1 + 1e-8f), r2 = 1.f/(d2 + 1e-8f);
  float rs = (r0 + r1) + r2;
  swts[t][0] = r0/rs; swts[t][1] = r1/rs; swts[t][2] = r2/rs;
  sidx[t][0] = i0;    sidx[t][1] = i1;    sidx[t][2] = i2;
  __syncthreads();

  // phase B: one wave per 64 queries; lanes cover the 256 channels (4 each)
  int w = t >> 6, lane = t & 63;
  for (int q = w*64; q < w*64 + 64; ++q){
    float wa = swts[q][0], wb = swts[q][1], wc = swts[q][2];
    int   j0 = sidx[q][0], j1 = sidx[q][1], j2 = sidx[q][2];
    const ushort4 u0 = *(const ushort4*)(p2t + (((size_t)b*SPTS + j0)<<8) + (lane<<2));
    const ushort4 u1 = *(const ushort4*)(p2t + (((size_t)b*SPTS + j1)<<8) + (lane<<2));
    const ushort4 u2 = *(const ushort4*)(p2t + (((size_t)b*SPTS + j2)<<8) + (lane<<2));
    ushort4 ov;
    ov.x = f2bf(wa*bf2f(u0.x) + wb*bf2f(u1.x) + wc*bf2f(u2.x));
    ov.y = f2bf(wa*bf2f(u0.y) + wb*bf2f(u1.y) + wc*bf2f(u2.y));
    ov.z = f2bf(wa*bf2f(u0.z) + wb*bf2f(u1.z) + wc*bf2f(u2.z));
    ov.w = f2bf(wa*bf2f(u0.w) + wb*bf2f(u1.w) + wc*bf2f(u2.w));
    *(ushort4*)(X + ((size_t)b*NPTS + n0 + q)*384 + 128 + (lane<<2)) = ov;
  }
}

// ---------------- 128x128-tile bf16 GEMM (m97 structure) + fused BN partial stats ----------------
// C[m][n] = sum_k A[m][k] * Bw[n][k];  A: (M,K) rows, Bw: (Nn,K) rows (= W), both bf16.
__global__ __launch_bounds__(256) void gemm_k(const u16* __restrict__ A, const u16* __restrict__ Bw,
                                              u16* __restrict__ Cc, int K, int Nn,
                                              float* __restrict__ gsum, float* __restrict__ gsq){
  __shared__ u16 lA[128*32];
  __shared__ u16 lB[128*32];
  __shared__ float sums[128];
  __shared__ float sqs[128];
  int t = threadIdx.x, lane = t & 63, wid = t >> 6;
  int rowBase = blockIdx.x << 7, colBase = blockIdx.y << 7;
  int wm = wid >> 1, wn = wid & 1;
  int rr = lane >> 2, cb = (lane & 3) << 4;

  const char* pA0 = (const char*)A  + (((size_t)(rowBase + wid*32 + rr) * K) << 1) + cb;
  const char* pA1 = pA0 + (((size_t)16 * K) << 1);
  const char* pB0 = (const char*)Bw + (((size_t)(colBase + wid*32 + rr) * K) << 1) + cb;
  const char* pB1 = pB0 + (((size_t)16 * K) << 1);
  char* dA0 = (char*)lA + wid*2048; char* dA1 = dA0 + 1024;
  char* dB0 = (char*)lB + wid*2048; char* dB1 = dB0 + 1024;

  f32x4 z = {0.f, 0.f, 0.f, 0.f};
  f32x4 acc[4][4];
  #pragma unroll
  for (int m = 0; m < 4; ++m)
    #pragma unroll
    for (int n = 0; n < 4; ++n) acc[m][n] = z;

  for (int kk = 0; kk < K; kk += 32){
    size_t ko = ((size_t)kk) << 1;
    __builtin_amdgcn_global_load_lds((const __attribute__((address_space(1))) void*)(pA0 + ko),
                                     (__attribute__((address_space(3))) void*)dA0, 16, 0, 0);
    __builtin_amdgcn_global_load_lds((const __attribute__((address_space(1))) void*)(pA1 + ko),
                                     (__attribute__((address_space(3))) void*)dA1, 16, 0, 0);
    __builtin_amdgcn_global_load_lds((const __attribute__((address_space(1))) void*)(pB0 + ko),
                                     (__attribute__((address_space(3))) void*)dB0, 16, 0, 0);
    __builtin_amdgcn_global_load_lds((const __attribute__((address_space(1))) void*)(pB1 + ko),
                                     (__attribute__((address_space(3))) void*)dB1, 16, 0, 0);
    __syncthreads();
    bf16x8 af[4], bfr[4];
    #pragma unroll
    for (int m = 0; m < 4; ++m)
      af[m] = *(const bf16x8*)(lA + ((wm*64 + m*16 + (lane & 15)) << 5) + ((lane >> 4) << 3));
    #pragma unroll
    for (int n = 0; n < 4; ++n)
      bfr[n] = *(const bf16x8*)(lB + ((wn*64 + n*16 + (lane & 15)) << 5) + ((lane >> 4) << 3));
    #pragma unroll
    for (int m = 0; m < 4; ++m)
      #pragma unroll
      for (int n = 0; n < 4; ++n)
        acc[m][n] = __builtin_amdgcn_mfma_f32_16x16x32_bf16(af[m], bfr[n], acc[m][n], 0, 0, 0);
    __syncthreads();
  }

  if (t < 128){ sums[t] = 0.f; sqs[t] = 0.f; }
  __syncthreads();
  size_t rb = (size_t)rowBase + wm*64 + ((lane >> 4) << 2);
  int cbase = colBase + wn*64 + (lane & 15);
  #pragma unroll
  for (int n = 0; n < 4; ++n){
    float s = 0.f, q = 0.f;
    #pragma unroll
    for (int m = 0; m < 4; ++m){
      #pragma unroll
      for (int r = 0; r < 4; ++r){
        float v = acc[m][n][r];
        Cc[(rb + m*16 + r)*(size_t)Nn + cbase + n*16] = f2bf(v);
        s += v; q += v*v;
      }
    }
    int cl = wn*64 + n*16 + (lane & 15);
    atomicAdd(&sums[cl], s); atomicAdd(&sqs[cl], q);
  }
  __syncthreads();
  if (t < 128){
    atomicAdd(&gsum[colBase + t], sums[t]);
    atomicAdd(&gsq [colBase + t], sqs[t]);
  }
}

// ---------------- per-channel BN scale/shift from (sum, sumsq); bias cancels in BN ----------------
__global__ void finalize_k(const float* __restrict__ sum, const float* __restrict__ sq,
                           const float* __restrict__ g, const float* __restrict__ bet,
                           float* __restrict__ sc, float* __restrict__ sh, int C){
  int t = threadIdx.x;
  if (t < C){
    const float inv = 1.f/65536.f;
    float mean = sum[t]*inv;
    float var  = sq[t]*inv - mean*mean;
    float rstd = rsqrtf(var + 1e-5f);
    float s = g[t]*rstd;
    sc[t] = s;
    sh[t] = bet[t] - mean*s;
  }
}

// ---------------- elementwise BN + relu, bf16 -> bf16 (C = 256) ----------------
__global__ __launch_bounds__(256) void bnrelu_k(const u16* __restrict__ y, u16* __restrict__ o,
                                                const float* __restrict__ sc, const float* __restrict__ sh){
  size_t i = ((size_t)blockIdx.x*256 + threadIdx.x)*8;
  ushort4 a = *(const ushort4*)(y + i);
  ushort4 b = *(const ushort4*)(y + i + 4);
  int c0 = (int)(i & 255);
  ushort4 oa, ob;
  float v;
  v = bf2f(a.x)*sc[c0+0] + sh[c0+0]; oa.x = f2bf(fmaxf(v, 0.f));
  v = bf2f(a.y)*sc[c0+1] + sh[c0+1]; oa.y = f2bf(fmaxf(v, 0.f));
  v = bf2f(a.z)*sc[c0+2] + sh[c0+2]; oa.z = f2bf(fmaxf(v, 0.f));
  v = bf2f(a.w)*sc[c0+3] + sh[c0+3]; oa.w = f2bf(fmaxf(v, 0.f));
  v = bf2f(b.x)*sc[c0+4] + sh[c0+4]; ob.x = f2bf(fmaxf(v, 0.f));
  v = bf2f(b.y)*sc[c0+5] + sh[c0+5]; ob.y = f2bf(fmaxf(v, 0.f));
  v = bf2f(b.z)*sc[c0+6] + sh[c0+6]; ob.z = f2bf(fmaxf(v, 0.f));
  v = bf2f(b.w)*sc[c0+7] + sh[c0+7]; ob.w = f2bf(fmaxf(v, 0.f));
  *(ushort4*)(o + i)     = oa;
  *(ushort4*)(o + i + 4) = ob;
}

// ---------------- BN2 + relu + transpose (BN,128) -> (B,128,N) fp32 out ----------------
__global__ __launch_bounds__(256) void finalout_k(const u16* __restrict__ y2, const float* __restrict__ sc,
                                                  const float* __restrict__ sh, float* __restrict__ out){
  __shared__ float tl[128][65];
  int t  = threadIdx.x;
  int b  = blockIdx.x >> 6;
  int n0 = (blockIdx.x & 63) << 6;
  for (int i = t; i < 8192; i += 256){
    int r = i >> 7, c = i & 127;
    float v = bf2f(y2[((size_t)b*NPTS + n0 + r)*128 + c]);
    v = fmaxf(v*sc[c] + sh[c], 0.f);
    tl[c][r] = v;
  }
  __syncthreads();
  for (int i = t; i < 8192; i += 256){
    int o = i >> 6, j = i & 63;
    out[(size_t)b*128*NPTS + (size_t)o*NPTS + n0 + j] = tl[o][j];
  }
}

extern "C" void kernel_launch(void* const* d_in, const int* in_sizes, int n_in,
                              void* d_out, int out_size, void* d_ws, size_t ws_size,
                              hipStream_t stream) {
  const float* xyz1    = (const float*)d_in[0];
  const float* xyz2    = (const float*)d_in[1];
  const float* points1 = (const float*)d_in[2];
  const float* points2 = (const float*)d_in[3];
  const float* w1      = (const float*)d_in[4];
  // d_in[5] = b1 (cancels in BN)
  const float* g1      = (const float*)d_in[6];
  const float* beta1   = (const float*)d_in[7];
  const float* w2      = (const float*)d_in[8];
  // d_in[9] = b2 (cancels in BN)
  const float* g2      = (const float*)d_in[10];
  const float* beta2   = (const float*)d_in[11];

  char* ws = (char*)d_ws;
  // layout (bytes):
  u16*  X    = (u16*)ws;                          // BN x 384 bf16 = 50,331,648
  u16*  Y1n  = (u16*)ws;                          // alias: BN x 256 bf16 = 33,554,432
  u16*  Y2   = (u16*)(ws + 33554432);             // BN x 128 bf16 = 16,777,216
  u16*  p2t  = (u16*)(ws + 50331648);             // B x S x 256 bf16 = 8,388,608
  u16*  Y1   = (u16*)(ws + 58720256);             // BN x 256 bf16 = 33,554,432
  u16*  w1b  = (u16*)(ws + 92274688);             // 196,608
  u16*  w2b  = (u16*)(ws + 92471296);             // 65,536
  float* st  = (float*)(ws + 92536832);           // stats: 1536 floats
  float* sum1 = st;        float* sq1 = st + 256;
  float* sum2 = st + 512;  float* sq2 = st + 640;
  float* sc1  = st + 768;  float* sh1 = st + 1024;
  float* sc2  = st + 1280; float* sh2 = st + 1408;

  hipMemsetAsync(st, 0, 768*sizeof(float), stream);

  convw_k<<<512, 256, 0, stream>>>(w1, w2, w1b, w2b);
  transpose_k<<<dim3(64, 16), 256, 0, stream>>>(points1, X,   128, NPTS, 384);
  transpose_k<<<dim3(16, 16), 256, 0, stream>>>(points2, p2t, 256, SPTS, 256);
  knn_k<<<512, 128, 0, stream>>>(xyz1, xyz2, p2t, X);
  gemm_k<<<dim3(512, 2), 256, 0, stream>>>(X, w1b, Y1, 384, 256, sum1, sq1);
  finalize_k<<<1, 256, 0, stream>>>(sum1, sq1, g1, beta1, sc1, sh1, 256);
  bnrelu_k<<<8192, 256, 0, stream>>>(Y1, Y1n, sc1, sh1);
  gemm_k<<<dim3(512, 1), 256, 0, stream>>>(Y1n, w2b, Y2, 256, 128, sum2, sq2);
  finalize_k<<<1, 256, 0, stream>>>(sum2, sq2, g2, beta2, sc2, sh2, 128);
  finalout_k<<<1024, 256, 0, stream>>>(Y2, sc2, sh2, (float*)d_out);
}

// Round 2
// 174.859 us; speedup vs baseline: 1.4343x; 1.4343x over previous
//
#include <hip/hip_runtime.h>

typedef unsigned short u16;
typedef unsigned int   u32;
typedef __attribute__((ext_vector_type(8))) short bf16x8;
typedef __attribute__((ext_vector_type(4))) float f32x4;

#define NB   16
#define NPTS 4096
#define SPTS 1024
#define BNT  65536   // NB*NPTS

__device__ __forceinline__ float bf2f(u16 u){ return __uint_as_float(((u32)u)<<16); }
__device__ __forceinline__ u16 f2bf(float f){
  u32 u = __float_as_uint(f);
  return (u16)((u + 0x7FFFu + ((u>>16)&1u))>>16);
}

// ---------------- W fp32 -> bf16 ----------------
__global__ __launch_bounds__(256) void convw_k(const float* __restrict__ w1, const float* __restrict__ w2,
                                               u16* __restrict__ w1b, u16* __restrict__ w2b){
  int i = blockIdx.x*256 + threadIdx.x;           // 131072 total
  if (i < 98304) w1b[i] = f2bf(w1[i]);
  else { int j = i - 98304; w2b[j] = f2bf(w2[j]); }
}

// ---------------- (B,C,S) fp32 -> rows (b*S+s)*ostride + c, bf16 ----------------
__global__ __launch_bounds__(256) void transpose_k(const float* __restrict__ in, u16* __restrict__ out,
                                                   int C, int S, int ostride){
  __shared__ float tl[64][65];
  int t = threadIdx.x;
  int b = blockIdx.y;
  int s0 = blockIdx.x * 64;
  for (int ct = 0; ct < C; ct += 64){
    __syncthreads();
    for (int i = t; i < 4096; i += 256){
      int sl = i & 63, cl = i >> 6;
      tl[sl][cl] = in[((size_t)b*C + ct + cl)*S + s0 + sl];
    }
    __syncthreads();
    for (int i = t; i < 4096; i += 256){
      int cl = i & 63, sl = i >> 6;
      out[((size_t)b*S + s0 + sl)*ostride + ct + cl] = f2bf(tl[sl][cl]);
    }
  }
}

// ---------------- 3-NN search (S split 4-way) + weighted feature interp -> X cols [128,384) ----------------
// Block: 512 threads = 4 chunk-groups x 128 queries. Each thread scans S/4=256 points;
// partial top-3 lists merged per query in LDS (iteration order preserves stable-top_k tie-break).
__global__ __launch_bounds__(512) void knn_k(const float* __restrict__ xyz1, const float* __restrict__ xyz2,
                                             const u16* __restrict__ p2t, u16* __restrict__ X){
  __shared__ float4 sxyz[SPTS];          // 16 KB
  __shared__ float  pd[128][4][3];       // 6 KB  partial dists
  __shared__ int    pi[128][4][3];       // 6 KB  partial idx
  __shared__ float  swts[128][3];
  __shared__ int    sidx[128][3];
  int t  = threadIdx.x;
  int b  = blockIdx.x >> 5;
  int n0 = (blockIdx.x & 31) << 7;
  const float* x2b = xyz2 + (size_t)b*3*SPTS;
  for (int s = t; s < SPTS; s += 512)
    sxyz[s] = make_float4(x2b[s], x2b[SPTS+s], x2b[2*SPTS+s], 0.f);
  int q = t & 127, g = t >> 7;           // query slot, chunk group
  const float* x1b = xyz1 + (size_t)b*3*NPTS;
  int n = n0 + q;
  float qx = x1b[n], qy = x1b[NPTS+n], qz = x1b[2*NPTS+n];
  __syncthreads();

  float d0=3.4e38f, d1=3.4e38f, d2=3.4e38f;
  int   i0=0, i1=0, i2=0;
  int sBeg = g << 8, sEnd = sBeg + 256;
  for (int s = sBeg; s < sEnd; ++s){
    float4 p = sxyz[s];
    float dist;
    {
      #pragma clang fp contract(off)
      float dx = qx - p.x, dy = qy - p.y, dz = qz - p.z;
      dist = ((dx*dx) + (dy*dy)) + (dz*dz);   // match numpy rounding exactly (no fma)
    }
    if (dist < d2){
      bool c1 = dist < d1, c0 = dist < d0;
      d2 = c1 ? d1 : dist;                 i2 = c1 ? i1 : s;
      float nd1 = c1 ? (c0 ? d0 : dist) : d1;
      int   ni1 = c1 ? (c0 ? i0 : s)    : i1;
      d0 = c0 ? dist : d0;                 i0 = c0 ? s : i0;
      d1 = nd1;                            i1 = ni1;
    }
  }
  pd[q][g][0]=d0; pd[q][g][1]=d1; pd[q][g][2]=d2;
  pi[q][g][0]=i0; pi[q][g][1]=i1; pi[q][g][2]=i2;
  __syncthreads();

  // merge 12 candidates per query (iteration order = ascending chunk, ascending list pos
  // => equal-d candidates seen in ascending index order; strict < keeps the first = stable top_k)
  if (t < 128){
    float m0=3.4e38f, m1=3.4e38f, m2=3.4e38f;
    int   j0=0, j1=0, j2=0;
    #pragma unroll
    for (int gg = 0; gg < 4; ++gg){
      #pragma unroll
      for (int p = 0; p < 3; ++p){
        float dist = pd[t][gg][p]; int s = pi[t][gg][p];
        if (dist < m2){
          bool c1 = dist < m1, c0 = dist < m0;
          m2 = c1 ? m1 : dist;                 j2 = c1 ? j1 : s;
          float nd1 = c1 ? (c0 ? m0 : dist) : m1;
          int   ni1 = c1 ? (c0 ? j0 : s)    : j1;
          m0 = c0 ? dist : m0;                 j0 = c0 ? s : j0;
          m1 = nd1;                            j1 = ni1;
        }
      }
    }
    float r0 = 1.f/(m0 + 1e-8f), r1 = 1.f/(m1 + 1e-8f), r2 = 1.f/(m2 + 1e-8f);
    float rs = (r0 + r1) + r2;
    swts[t][0] = r0/rs; swts[t][1] = r1/rs; swts[t][2] = r2/rs;
    sidx[t][0] = j0;    sidx[t][1] = j1;    sidx[t][2] = j2;
  }
  __syncthreads();

  // phase B: 8 waves; each wave handles 16 queries; lanes cover the 256 channels (4 each)
  int w = t >> 6, lane = t & 63;
  for (int qq = w*16; qq < w*16 + 16; ++qq){
    float wa = swts[qq][0], wb = swts[qq][1], wc = swts[qq][2];
    int   j0 = sidx[qq][0], j1 = sidx[qq][1], j2 = sidx[qq][2];
    const ushort4 u0 = *(const ushort4*)(p2t + (((size_t)b*SPTS + j0)<<8) + (lane<<2));
    const ushort4 u1 = *(const ushort4*)(p2t + (((size_t)b*SPTS + j1)<<8) + (lane<<2));
    const ushort4 u2 = *(const ushort4*)(p2t + (((size_t)b*SPTS + j2)<<8) + (lane<<2));
    ushort4 ov;
    ov.x = f2bf(wa*bf2f(u0.x) + wb*bf2f(u1.x) + wc*bf2f(u2.x));
    ov.y = f2bf(wa*bf2f(u0.y) + wb*bf2f(u1.y) + wc*bf2f(u2.y));
    ov.z = f2bf(wa*bf2f(u0.z) + wb*bf2f(u1.z) + wc*bf2f(u2.z));
    ov.w = f2bf(wa*bf2f(u0.w) + wb*bf2f(u1.w) + wc*bf2f(u2.w));
    *(ushort4*)(X + ((size_t)b*NPTS + n0 + qq)*384 + 128 + (lane<<2)) = ov;
  }
}

// ---------------- 128x128-tile bf16 GEMM (m97 structure) + fused BN partial stats ----------------
// C[m][n] = sum_k A[m][k] * Bw[n][k];  A: (M,K) rows, Bw: (Nn,K) rows (= W), both bf16.
__global__ __launch_bounds__(256) void gemm_k(const u16* __restrict__ A, const u16* __restrict__ Bw,
                                              u16* __restrict__ Cc, int K, int Nn,
                                              float* __restrict__ gsum, float* __restrict__ gsq){
  __shared__ u16 lA[128*32];
  __shared__ u16 lB[128*32];
  __shared__ float sums[128];
  __shared__ float sqs[128];
  int t = threadIdx.x, lane = t & 63, wid = t >> 6;
  int rowBase = blockIdx.x << 7, colBase = blockIdx.y << 7;
  int wm = wid >> 1, wn = wid & 1;
  int rr = lane >> 2, cb = (lane & 3) << 4;

  const char* pA0 = (const char*)A  + (((size_t)(rowBase + wid*32 + rr) * K) << 1) + cb;
  const char* pA1 = pA0 + (((size_t)16 * K) << 1);
  const char* pB0 = (const char*)Bw + (((size_t)(colBase + wid*32 + rr) * K) << 1) + cb;
  const char* pB1 = pB0 + (((size_t)16 * K) << 1);
  char* dA0 = (char*)lA + wid*2048; char* dA1 = dA0 + 1024;
  char* dB0 = (char*)lB + wid*2048; char* dB1 = dB0 + 1024;

  f32x4 z = {0.f, 0.f, 0.f, 0.f};
  f32x4 acc[4][4];
  #pragma unroll
  for (int m = 0; m < 4; ++m)
    #pragma unroll
    for (int n = 0; n < 4; ++n) acc[m][n] = z;

  for (int kk = 0; kk < K; kk += 32){
    size_t ko = ((size_t)kk) << 1;
    __builtin_amdgcn_global_load_lds((const __attribute__((address_space(1))) void*)(pA0 + ko),
                                     (__attribute__((address_space(3))) void*)dA0, 16, 0, 0);
    __builtin_amdgcn_global_load_lds((const __attribute__((address_space(1))) void*)(pA1 + ko),
                                     (__attribute__((address_space(3))) void*)dA1, 16, 0, 0);
    __builtin_amdgcn_global_load_lds((const __attribute__((address_space(1))) void*)(pB0 + ko),
                                     (__attribute__((address_space(3))) void*)dB0, 16, 0, 0);
    __builtin_amdgcn_global_load_lds((const __attribute__((address_space(1))) void*)(pB1 + ko),
                                     (__attribute__((address_space(3))) void*)dB1, 16, 0, 0);
    __syncthreads();
    bf16x8 af[4], bfr[4];
    #pragma unroll
    for (int m = 0; m < 4; ++m)
      af[m] = *(const bf16x8*)(lA + ((wm*64 + m*16 + (lane & 15)) << 5) + ((lane >> 4) << 3));
    #pragma unroll
    for (int n = 0; n < 4; ++n)
      bfr[n] = *(const bf16x8*)(lB + ((wn*64 + n*16 + (lane & 15)) << 5) + ((lane >> 4) << 3));
    #pragma unroll
    for (int m = 0; m < 4; ++m)
      #pragma unroll
      for (int n = 0; n < 4; ++n)
        acc[m][n] = __builtin_amdgcn_mfma_f32_16x16x32_bf16(af[m], bfr[n], acc[m][n], 0, 0, 0);
    __syncthreads();
  }

  if (t < 128){ sums[t] = 0.f; sqs[t] = 0.f; }
  __syncthreads();
  size_t rb = (size_t)rowBase + wm*64 + ((lane >> 4) << 2);
  int cbase = colBase + wn*64 + (lane & 15);
  #pragma unroll
  for (int n = 0; n < 4; ++n){
    float s = 0.f, q = 0.f;
    #pragma unroll
    for (int m = 0; m < 4; ++m){
      #pragma unroll
      for (int r = 0; r < 4; ++r){
        float v = acc[m][n][r];
        Cc[(rb + m*16 + r)*(size_t)Nn + cbase + n*16] = f2bf(v);
        s += v; q += v*v;
      }
    }
    int cl = wn*64 + n*16 + (lane & 15);
    atomicAdd(&sums[cl], s); atomicAdd(&sqs[cl], q);
  }
  __syncthreads();
  if (t < 128){
    atomicAdd(&gsum[colBase + t], sums[t]);
    atomicAdd(&gsq [colBase + t], sqs[t]);
  }
}

// ---------------- per-channel BN scale/shift from (sum, sumsq); bias cancels in BN ----------------
__global__ void finalize_k(const float* __restrict__ sum, const float* __restrict__ sq,
                           const float* __restrict__ g, const float* __restrict__ bet,
                           float* __restrict__ sc, float* __restrict__ sh, int C){
  int t = threadIdx.x;
  if (t < C){
    const float inv = 1.f/65536.f;
    float mean = sum[t]*inv;
    float var  = sq[t]*inv - mean*mean;
    float rstd = rsqrtf(var + 1e-5f);
    float s = g[t]*rstd;
    sc[t] = s;
    sh[t] = bet[t] - mean*s;
  }
}

// ---------------- elementwise BN + relu, bf16 -> bf16 (C = 256) ----------------
__global__ __launch_bounds__(256) void bnrelu_k(const u16* __restrict__ y, u16* __restrict__ o,
                                                const float* __restrict__ sc, const float* __restrict__ sh){
  size_t i = ((size_t)blockIdx.x*256 + threadIdx.x)*8;
  ushort4 a = *(const ushort4*)(y + i);
  ushort4 b = *(const ushort4*)(y + i + 4);
  int c0 = (int)(i & 255);
  ushort4 oa, ob;
  float v;
  v = bf2f(a.x)*sc[c0+0] + sh[c0+0]; oa.x = f2bf(fmaxf(v, 0.f));
  v = bf2f(a.y)*sc[c0+1] + sh[c0+1]; oa.y = f2bf(fmaxf(v, 0.f));
  v = bf2f(a.z)*sc[c0+2] + sh[c0+2]; oa.z = f2bf(fmaxf(v, 0.f));
  v = bf2f(a.w)*sc[c0+3] + sh[c0+3]; oa.w = f2bf(fmaxf(v, 0.f));
  v = bf2f(b.x)*sc[c0+4] + sh[c0+4]; ob.x = f2bf(fmaxf(v, 0.f));
  v = bf2f(b.y)*sc[c0+5] + sh[c0+5]; ob.y = f2bf(fmaxf(v, 0.f));
  v = bf2f(b.z)*sc[c0+6] + sh[c0+6]; ob.z = f2bf(fmaxf(v, 0.f));
  v = bf2f(b.w)*sc[c0+7] + sh[c0+7]; ob.w = f2bf(fmaxf(v, 0.f));
  *(ushort4*)(o + i)     = oa;
  *(ushort4*)(o + i + 4) = ob;
}

// ---------------- BN2 + relu + transpose (BN,128) -> (B,128,N) fp32 out ----------------
__global__ __launch_bounds__(256) void finalout_k(const u16* __restrict__ y2, const float* __restrict__ sc,
                                                  const float* __restrict__ sh, float* __restrict__ out){
  __shared__ float tl[128][65];
  int t  = threadIdx.x;
  int b  = blockIdx.x >> 6;
  int n0 = (blockIdx.x & 63) << 6;
  for (int i = t; i < 8192; i += 256){
    int r = i >> 7, c = i & 127;
    float v = bf2f(y2[((size_t)b*NPTS + n0 + r)*128 + c]);
    v = fmaxf(v*sc[c] + sh[c], 0.f);
    tl[c][r] = v;
  }
  __syncthreads();
  for (int i = t; i < 8192; i += 256){
    int o = i >> 6, j = i & 63;
    out[(size_t)b*128*NPTS + (size_t)o*NPTS + n0 + j] = tl[o][j];
  }
}

extern "C" void kernel_launch(void* const* d_in, const int* in_sizes, int n_in,
                              void* d_out, int out_size, void* d_ws, size_t ws_size,
                              hipStream_t stream) {
  const float* xyz1    = (const float*)d_in[0];
  const float* xyz2    = (const float*)d_in[1];
  const float* points1 = (const float*)d_in[2];
  const float* points2 = (const float*)d_in[3];
  const float* w1      = (const float*)d_in[4];
  // d_in[5] = b1 (cancels in BN)
  const float* g1      = (const float*)d_in[6];
  const float* beta1   = (const float*)d_in[7];
  const float* w2      = (const float*)d_in[8];
  // d_in[9] = b2 (cancels in BN)
  const float* g2      = (const float*)d_in[10];
  const float* beta2   = (const float*)d_in[11];

  char* ws = (char*)d_ws;
  // layout (bytes):
  u16*  X    = (u16*)ws;                          // BN x 384 bf16 = 50,331,648
  u16*  Y1n  = (u16*)ws;                          // alias: BN x 256 bf16 = 33,554,432
  u16*  Y2   = (u16*)(ws + 33554432);             // BN x 128 bf16 = 16,777,216
  u16*  p2t  = (u16*)(ws + 50331648);             // B x S x 256 bf16 = 8,388,608
  u16*  Y1   = (u16*)(ws + 58720256);             // BN x 256 bf16 = 33,554,432
  u16*  w1b  = (u16*)(ws + 92274688);             // 196,608
  u16*  w2b  = (u16*)(ws + 92471296);             // 65,536
  float* st  = (float*)(ws + 92536832);           // stats: 1536 floats
  float* sum1 = st;        float* sq1 = st + 256;
  float* sum2 = st + 512;  float* sq2 = st + 640;
  float* sc1  = st + 768;  float* sh1 = st + 1024;
  float* sc2  = st + 1280; float* sh2 = st + 1408;

  hipMemsetAsync(st, 0, 768*sizeof(float), stream);

  convw_k<<<512, 256, 0, stream>>>(w1, w2, w1b, w2b);
  transpose_k<<<dim3(64, 16), 256, 0, stream>>>(points1, X,   128, NPTS, 384);
  transpose_k<<<dim3(16, 16), 256, 0, stream>>>(points2, p2t, 256, SPTS, 256);
  knn_k<<<512, 512, 0, stream>>>(xyz1, xyz2, p2t, X);
  gemm_k<<<dim3(512, 2), 256, 0, stream>>>(X, w1b, Y1, 384, 256, sum1, sq1);
  finalize_k<<<1, 256, 0, stream>>>(sum1, sq1, g1, beta1, sc1, sh1, 256);
  bnrelu_k<<<8192, 256, 0, stream>>>(Y1, Y1n, sc1, sh1);
  gemm_k<<<dim3(512, 1), 256, 0, stream>>>(Y1n, w2b, Y2, 256, 128, sum2, sq2);
  finalize_k<<<1, 256, 0, stream>>>(sum2, sq2, g2, beta2, sc2, sh2, 128);
  finalout_k<<<1024, 256, 0, stream>>>(Y2, sc2, sh2, (float*)d_out);
}

// Round 3
// 168.119 us; speedup vs baseline: 1.4918x; 1.0401x over previous
//
#include <hip/hip_runtime.h>

typedef unsigned short u16;
typedef unsigned int   u32;
typedef __attribute__((ext_vector_type(8))) short bf16x8;
typedef __attribute__((ext_vector_type(4))) float f32x4;

#define NB   16
#define NPTS 4096
#define SPTS 1024
#define BNT  65536   // NB*NPTS

__device__ __forceinline__ float bf2f(u16 u){ return __uint_as_float(((u32)u)<<16); }
__device__ __forceinline__ u16 f2bf(float f){
  u32 u = __float_as_uint(f);
  return (u16)((u + 0x7FFFu + ((u>>16)&1u))>>16);
}

// ---------------- W fp32 -> bf16 ----------------
__global__ __launch_bounds__(256) void convw_k(const float* __restrict__ w1, const float* __restrict__ w2,
                                               u16* __restrict__ w1b, u16* __restrict__ w2b){
  int i = blockIdx.x*256 + threadIdx.x;           // 131072 total
  if (i < 98304) w1b[i] = f2bf(w1[i]);
  else { int j = i - 98304; w2b[j] = f2bf(w2[j]); }
}

// ---------------- (B,C,S) fp32 -> rows (b*S+s)*ostride + c, bf16 ----------------
__global__ __launch_bounds__(256) void transpose_k(const float* __restrict__ in, u16* __restrict__ out,
                                                   int C, int S, int ostride){
  __shared__ float tl[64][65];
  int t = threadIdx.x;
  int b = blockIdx.y;
  int s0 = blockIdx.x * 64;
  for (int ct = 0; ct < C; ct += 64){
    __syncthreads();
    for (int i = t; i < 4096; i += 256){
      int sl = i & 63, cl = i >> 6;
      tl[sl][cl] = in[((size_t)b*C + ct + cl)*S + s0 + sl];
    }
    __syncthreads();
    for (int i = t; i < 4096; i += 256){
      int cl = i & 63, sl = i >> 6;
      out[((size_t)b*S + s0 + sl)*ostride + ct + cl] = f2bf(tl[sl][cl]);
    }
  }
}

// ---------------- 3-NN search (S split 8-way, 64 queries/block) + interp -> X cols [128,384) ----------------
// Block: 512 threads = 8 chunk-groups x 64 queries (one wave per chunk-group).
// Each thread scans S/8=128 points; 8 partial top-3 lists merged per query (stable order).
// Grid: 16*64 = 1024 blocks = 4 blocks/CU -> 100% occupancy cap.
__global__ __launch_bounds__(512) void knn_k(const float* __restrict__ xyz1, const float* __restrict__ xyz2,
                                             const u16* __restrict__ p2t, u16* __restrict__ X){
  __shared__ float4 sxyz[SPTS];          // 16 KB
  __shared__ float  pd[8][3][64];        // 6 KB  partial dists (lane-major: conflict-free)
  __shared__ int    pi[8][3][64];        // 6 KB  partial idx
  __shared__ float  swts[3][64];
  __shared__ int    sidx[3][64];
  int t  = threadIdx.x;
  int b  = blockIdx.x >> 6;
  int n0 = (blockIdx.x & 63) << 6;
  const float* x2b = xyz2 + (size_t)b*3*SPTS;
  for (int s = t; s < SPTS; s += 512)
    sxyz[s] = make_float4(x2b[s], x2b[SPTS+s], x2b[2*SPTS+s], 0.f);
  int q = t & 63, g = t >> 6;            // query slot, chunk group (= wave id)
  const float* x1b = xyz1 + (size_t)b*3*NPTS;
  int n = n0 + q;
  float qx = x1b[n], qy = x1b[NPTS+n], qz = x1b[2*NPTS+n];
  __syncthreads();

  float d0=3.4e38f, d1=3.4e38f, d2=3.4e38f;
  int   i0=0, i1=0, i2=0;
  int sBeg = g << 7, sEnd = sBeg + 128;
  for (int s = sBeg; s < sEnd; ++s){
    float4 p = sxyz[s];
    float dist;
    {
      #pragma clang fp contract(off)
      float dx = qx - p.x, dy = qy - p.y, dz = qz - p.z;
      dist = ((dx*dx) + (dy*dy)) + (dz*dz);   // match numpy rounding exactly (no fma)
    }
    if (dist < d2){
      bool c1 = dist < d1, c0 = dist < d0;
      d2 = c1 ? d1 : dist;                 i2 = c1 ? i1 : s;
      float nd1 = c1 ? (c0 ? d0 : dist) : d1;
      int   ni1 = c1 ? (c0 ? i0 : s)    : i1;
      d0 = c0 ? dist : d0;                 i0 = c0 ? s : i0;
      d1 = nd1;                            i1 = ni1;
    }
  }
  pd[g][0][q]=d0; pd[g][1][q]=d1; pd[g][2][q]=d2;
  pi[g][0][q]=i0; pi[g][1][q]=i1; pi[g][2][q]=i2;
  __syncthreads();

  // merge 24 candidates per query (ascending chunk, ascending list pos
  // => equal-d candidates seen in ascending index order; strict < keeps the first = stable top_k)
  if (t < 64){
    float m0=3.4e38f, m1=3.4e38f, m2=3.4e38f;
    int   j0=0, j1=0, j2=0;
    #pragma unroll
    for (int gg = 0; gg < 8; ++gg){
      #pragma unroll
      for (int p = 0; p < 3; ++p){
        float dist = pd[gg][p][t]; int s = pi[gg][p][t];
        if (dist < m2){
          bool c1 = dist < m1, c0 = dist < m0;
          m2 = c1 ? m1 : dist;                 j2 = c1 ? j1 : s;
          float nd1 = c1 ? (c0 ? m0 : dist) : m1;
          int   ni1 = c1 ? (c0 ? j0 : s)    : j1;
          m0 = c0 ? dist : m0;                 j0 = c0 ? s : j0;
          m1 = nd1;                            j1 = ni1;
        }
      }
    }
    float r0 = 1.f/(m0 + 1e-8f), r1 = 1.f/(m1 + 1e-8f), r2 = 1.f/(m2 + 1e-8f);
    float rs = (r0 + r1) + r2;
    swts[0][t] = r0/rs; swts[1][t] = r1/rs; swts[2][t] = r2/rs;
    sidx[0][t] = j0;    sidx[1][t] = j1;    sidx[2][t] = j2;
  }
  __syncthreads();

  // phase B: 8 waves; each wave handles 8 queries; lanes cover the 256 channels (4 each)
  int w = t >> 6, lane = t & 63;
  for (int qq = w*8; qq < w*8 + 8; ++qq){
    float wa = swts[0][qq], wb = swts[1][qq], wc = swts[2][qq];
    int   j0 = sidx[0][qq], j1 = sidx[1][qq], j2 = sidx[2][qq];
    const ushort4 u0 = *(const ushort4*)(p2t + (((size_t)b*SPTS + j0)<<8) + (lane<<2));
    const ushort4 u1 = *(const ushort4*)(p2t + (((size_t)b*SPTS + j1)<<8) + (lane<<2));
    const ushort4 u2 = *(const ushort4*)(p2t + (((size_t)b*SPTS + j2)<<8) + (lane<<2));
    ushort4 ov;
    ov.x = f2bf(wa*bf2f(u0.x) + wb*bf2f(u1.x) + wc*bf2f(u2.x));
    ov.y = f2bf(wa*bf2f(u0.y) + wb*bf2f(u1.y) + wc*bf2f(u2.y));
    ov.z = f2bf(wa*bf2f(u0.z) + wb*bf2f(u1.z) + wc*bf2f(u2.z));
    ov.w = f2bf(wa*bf2f(u0.w) + wb*bf2f(u1.w) + wc*bf2f(u2.w));
    *(ushort4*)(X + ((size_t)b*NPTS + n0 + qq)*384 + 128 + (lane<<2)) = ov;
  }
}

// ---------------- 128x128-tile bf16 GEMM (m97 structure) + fused BN partial stats ----------------
// C[m][n] = sum_k A[m][k] * Bw[n][k];  A: (M,K) rows, Bw: (Nn,K) rows (= W), both bf16.
__global__ __launch_bounds__(256) void gemm_k(const u16* __restrict__ A, const u16* __restrict__ Bw,
                                              u16* __restrict__ Cc, int K, int Nn,
                                              float* __restrict__ gsum, float* __restrict__ gsq){
  __shared__ u16 lA[128*32];
  __shared__ u16 lB[128*32];
  __shared__ float sums[128];
  __shared__ float sqs[128];
  int t = threadIdx.x, lane = t & 63, wid = t >> 6;
  int rowBase = blockIdx.x << 7, colBase = blockIdx.y << 7;
  int wm = wid >> 1, wn = wid & 1;
  int rr = lane >> 2, cb = (lane & 3) << 4;

  const char* pA0 = (const char*)A  + (((size_t)(rowBase + wid*32 + rr) * K) << 1) + cb;
  const char* pA1 = pA0 + (((size_t)16 * K) << 1);
  const char* pB0 = (const char*)Bw + (((size_t)(colBase + wid*32 + rr) * K) << 1) + cb;
  const char* pB1 = pB0 + (((size_t)16 * K) << 1);
  char* dA0 = (char*)lA + wid*2048; char* dA1 = dA0 + 1024;
  char* dB0 = (char*)lB + wid*2048; char* dB1 = dB0 + 1024;

  f32x4 z = {0.f, 0.f, 0.f, 0.f};
  f32x4 acc[4][4];
  #pragma unroll
  for (int m = 0; m < 4; ++m)
    #pragma unroll
    for (int n = 0; n < 4; ++n) acc[m][n] = z;

  for (int kk = 0; kk < K; kk += 32){
    size_t ko = ((size_t)kk) << 1;
    __builtin_amdgcn_global_load_lds((const __attribute__((address_space(1))) void*)(pA0 + ko),
                                     (__attribute__((address_space(3))) void*)dA0, 16, 0, 0);
    __builtin_amdgcn_global_load_lds((const __attribute__((address_space(1))) void*)(pA1 + ko),
                                     (__attribute__((address_space(3))) void*)dA1, 16, 0, 0);
    __builtin_amdgcn_global_load_lds((const __attribute__((address_space(1))) void*)(pB0 + ko),
                                     (__attribute__((address_space(3))) void*)dB0, 16, 0, 0);
    __builtin_amdgcn_global_load_lds((const __attribute__((address_space(1))) void*)(pB1 + ko),
                                     (__attribute__((address_space(3))) void*)dB1, 16, 0, 0);
    __syncthreads();
    bf16x8 af[4], bfr[4];
    #pragma unroll
    for (int m = 0; m < 4; ++m)
      af[m] = *(const bf16x8*)(lA + ((wm*64 + m*16 + (lane & 15)) << 5) + ((lane >> 4) << 3));
    #pragma unroll
    for (int n = 0; n < 4; ++n)
      bfr[n] = *(const bf16x8*)(lB + ((wn*64 + n*16 + (lane & 15)) << 5) + ((lane >> 4) << 3));
    #pragma unroll
    for (int m = 0; m < 4; ++m)
      #pragma unroll
      for (int n = 0; n < 4; ++n)
        acc[m][n] = __builtin_amdgcn_mfma_f32_16x16x32_bf16(af[m], bfr[n], acc[m][n], 0, 0, 0);
    __syncthreads();
  }

  if (t < 128){ sums[t] = 0.f; sqs[t] = 0.f; }
  __syncthreads();
  size_t rb = (size_t)rowBase + wm*64 + ((lane >> 4) << 2);
  int cbase = colBase + wn*64 + (lane & 15);
  #pragma unroll
  for (int n = 0; n < 4; ++n){
    float s = 0.f, q = 0.f;
    #pragma unroll
    for (int m = 0; m < 4; ++m){
      #pragma unroll
      for (int r = 0; r < 4; ++r){
        float v = acc[m][n][r];
        Cc[(rb + m*16 + r)*(size_t)Nn + cbase + n*16] = f2bf(v);
        s += v; q += v*v;
      }
    }
    int cl = wn*64 + n*16 + (lane & 15);
    atomicAdd(&sums[cl], s); atomicAdd(&sqs[cl], q);
  }
  __syncthreads();
  if (t < 128){
    atomicAdd(&gsum[colBase + t], sums[t]);
    atomicAdd(&gsq [colBase + t], sqs[t]);
  }
}

// ---------------- per-channel BN scale/shift from (sum, sumsq); bias cancels in BN ----------------
__global__ void finalize_k(const float* __restrict__ sum, const float* __restrict__ sq,
                           const float* __restrict__ g, const float* __restrict__ bet,
                           float* __restrict__ sc, float* __restrict__ sh, int C){
  int t = threadIdx.x;
  if (t < C){
    const float inv = 1.f/65536.f;
    float mean = sum[t]*inv;
    float var  = sq[t]*inv - mean*mean;
    float rstd = rsqrtf(var + 1e-5f);
    float s = g[t]*rstd;
    sc[t] = s;
    sh[t] = bet[t] - mean*s;
  }
}

// ---------------- elementwise BN + relu, bf16 -> bf16 (C = 256) ----------------
__global__ __launch_bounds__(256) void bnrelu_k(const u16* __restrict__ y, u16* __restrict__ o,
                                                const float* __restrict__ sc, const float* __restrict__ sh){
  size_t i = ((size_t)blockIdx.x*256 + threadIdx.x)*8;
  ushort4 a = *(const ushort4*)(y + i);
  ushort4 b = *(const ushort4*)(y + i + 4);
  int c0 = (int)(i & 255);
  ushort4 oa, ob;
  float v;
  v = bf2f(a.x)*sc[c0+0] + sh[c0+0]; oa.x = f2bf(fmaxf(v, 0.f));
  v = bf2f(a.y)*sc[c0+1] + sh[c0+1]; oa.y = f2bf(fmaxf(v, 0.f));
  v = bf2f(a.z)*sc[c0+2] + sh[c0+2]; oa.z = f2bf(fmaxf(v, 0.f));
  v = bf2f(a.w)*sc[c0+3] + sh[c0+3]; oa.w = f2bf(fmaxf(v, 0.f));
  v = bf2f(b.x)*sc[c0+4] + sh[c0+4]; ob.x = f2bf(fmaxf(v, 0.f));
  v = bf2f(b.y)*sc[c0+5] + sh[c0+5]; ob.y = f2bf(fmaxf(v, 0.f));
  v = bf2f(b.z)*sc[c0+6] + sh[c0+6]; ob.z = f2bf(fmaxf(v, 0.f));
  v = bf2f(b.w)*sc[c0+7] + sh[c0+7]; ob.w = f2bf(fmaxf(v, 0.f));
  *(ushort4*)(o + i)     = oa;
  *(ushort4*)(o + i + 4) = ob;
}

// ---------------- BN2 + relu + transpose (BN,128) -> (B,128,N) fp32 out ----------------
__global__ __launch_bounds__(256) void finalout_k(const u16* __restrict__ y2, const float* __restrict__ sc,
                                                  const float* __restrict__ sh, float* __restrict__ out){
  __shared__ float tl[128][65];
  int t  = threadIdx.x;
  int b  = blockIdx.x >> 6;
  int n0 = (blockIdx.x & 63) << 6;
  for (int i = t; i < 8192; i += 256){
    int r = i >> 7, c = i & 127;
    float v = bf2f(y2[((size_t)b*NPTS + n0 + r)*128 + c]);
    v = fmaxf(v*sc[c] + sh[c], 0.f);
    tl[c][r] = v;
  }
  __syncthreads();
  for (int i = t; i < 8192; i += 256){
    int o = i >> 6, j = i & 63;
    out[(size_t)b*128*NPTS + (size_t)o*NPTS + n0 + j] = tl[o][j];
  }
}

extern "C" void kernel_launch(void* const* d_in, const int* in_sizes, int n_in,
                              void* d_out, int out_size, void* d_ws, size_t ws_size,
                              hipStream_t stream) {
  const float* xyz1    = (const float*)d_in[0];
  const float* xyz2    = (const float*)d_in[1];
  const float* points1 = (const float*)d_in[2];
  const float* points2 = (const float*)d_in[3];
  const float* w1      = (const float*)d_in[4];
  // d_in[5] = b1 (cancels in BN)
  const float* g1      = (const float*)d_in[6];
  const float* beta1   = (const float*)d_in[7];
  const float* w2      = (const float*)d_in[8];
  // d_in[9] = b2 (cancels in BN)
  const float* g2      = (const float*)d_in[10];
  const float* beta2   = (const float*)d_in[11];

  char* ws = (char*)d_ws;
  // layout (bytes):
  u16*  X    = (u16*)ws;                          // BN x 384 bf16 = 50,331,648
  u16*  Y1n  = (u16*)ws;                          // alias: BN x 256 bf16 = 33,554,432
  u16*  Y2   = (u16*)(ws + 33554432);             // BN x 128 bf16 = 16,777,216
  u16*  p2t  = (u16*)(ws + 50331648);             // B x S x 256 bf16 = 8,388,608
  u16*  Y1   = (u16*)(ws + 58720256);             // BN x 256 bf16 = 33,554,432
  u16*  w1b  = (u16*)(ws + 92274688);             // 196,608
  u16*  w2b  = (u16*)(ws + 92471296);             // 65,536
  float* st  = (float*)(ws + 92536832);           // stats: 1536 floats
  float* sum1 = st;        float* sq1 = st + 256;
  float* sum2 = st + 512;  float* sq2 = st + 640;
  float* sc1  = st + 768;  float* sh1 = st + 1024;
  float* sc2  = st + 1280; float* sh2 = st + 1408;

  hipMemsetAsync(st, 0, 768*sizeof(float), stream);

  convw_k<<<512, 256, 0, stream>>>(w1, w2, w1b, w2b);
  transpose_k<<<dim3(64, 16), 256, 0, stream>>>(points1, X,   128, NPTS, 384);
  transpose_k<<<dim3(16, 16), 256, 0, stream>>>(points2, p2t, 256, SPTS, 256);
  knn_k<<<1024, 512, 0, stream>>>(xyz1, xyz2, p2t, X);
  gemm_k<<<dim3(512, 2), 256, 0, stream>>>(X, w1b, Y1, 384, 256, sum1, sq1);
  finalize_k<<<1, 256, 0, stream>>>(sum1, sq1, g1, beta1, sc1, sh1, 256);
  bnrelu_k<<<8192, 256, 0, stream>>>(Y1, Y1n, sc1, sh1);
  gemm_k<<<dim3(512, 1), 256, 0, stream>>>(Y1n, w2b, Y2, 256, 128, sum2, sq2);
  finalize_k<<<1, 256, 0, stream>>>(sum2, sq2, g2, beta2, sc2, sh2, 128);
  finalout_k<<<1024, 256, 0, stream>>>(Y2, sc2, sh2, (float*)d_out);
}

// Round 4
// 154.862 us; speedup vs baseline: 1.6196x; 1.0856x over previous
//
#include <hip/hip_runtime.h>

typedef unsigned short u16;
typedef unsigned int   u32;
typedef __attribute__((ext_vector_type(8))) short bf16x8;
typedef __attribute__((ext_vector_type(8))) unsigned short u16x8;
typedef __attribute__((ext_vector_type(4))) float f32x4;

#define NB   16
#define NPTS 4096
#define SPTS 1024
#define BNT  65536   // NB*NPTS

__device__ __forceinline__ float bf2f(u16 u){ return __uint_as_float(((u32)u)<<16); }
__device__ __forceinline__ u16 f2bf(float f){
  u32 u = __float_as_uint(f);
  return (u16)((u + 0x7FFFu + ((u>>16)&1u))>>16);
}

// ---------------- W fp32 -> bf16 ----------------
__global__ __launch_bounds__(256) void convw_k(const float* __restrict__ w1, const float* __restrict__ w2,
                                               u16* __restrict__ w1b, u16* __restrict__ w2b){
  int i = blockIdx.x*256 + threadIdx.x;           // 131072 total
  if (i < 98304) w1b[i] = f2bf(w1[i]);
  else { int j = i - 98304; w2b[j] = f2bf(w2[j]); }
}

// ---------------- (B,C,S) fp32 -> rows (b*S+s)*ostride + c, bf16 ----------------
__global__ __launch_bounds__(256) void transpose_k(const float* __restrict__ in, u16* __restrict__ out,
                                                   int C, int S, int ostride){
  __shared__ float tl[64][65];
  int t = threadIdx.x;
  int b = blockIdx.y;
  int s0 = blockIdx.x * 64;
  for (int ct = 0; ct < C; ct += 64){
    __syncthreads();
    for (int i = t; i < 4096; i += 256){
      int sl = i & 63, cl = i >> 6;
      tl[sl][cl] = in[((size_t)b*C + ct + cl)*S + s0 + sl];
    }
    __syncthreads();
    for (int i = t; i < 4096; i += 256){
      int cl = i & 63, sl = i >> 6;
      out[((size_t)b*S + s0 + sl)*ostride + ct + cl] = f2bf(tl[sl][cl]);
    }
  }
}

// ---------------- 3-NN search (S split 8-way, 64 queries/block) + interp -> X cols [128,384) ----------------
__global__ __launch_bounds__(512) void knn_k(const float* __restrict__ xyz1, const float* __restrict__ xyz2,
                                             const u16* __restrict__ p2t, u16* __restrict__ X){
  __shared__ float4 sxyz[SPTS];          // 16 KB
  __shared__ float  pd[8][3][64];
  __shared__ int    pi[8][3][64];
  __shared__ float  swts[3][64];
  __shared__ int    sidx[3][64];
  int t  = threadIdx.x;
  int b  = blockIdx.x >> 6;
  int n0 = (blockIdx.x & 63) << 6;
  const float* x2b = xyz2 + (size_t)b*3*SPTS;
  for (int s = t; s < SPTS; s += 512)
    sxyz[s] = make_float4(x2b[s], x2b[SPTS+s], x2b[2*SPTS+s], 0.f);
  int q = t & 63, g = t >> 6;
  const float* x1b = xyz1 + (size_t)b*3*NPTS;
  int n = n0 + q;
  float qx = x1b[n], qy = x1b[NPTS+n], qz = x1b[2*NPTS+n];
  __syncthreads();

  float d0=3.4e38f, d1=3.4e38f, d2=3.4e38f;
  int   i0=0, i1=0, i2=0;
  int sBeg = g << 7, sEnd = sBeg + 128;
  for (int s = sBeg; s < sEnd; ++s){
    float4 p = sxyz[s];
    float dist;
    {
      #pragma clang fp contract(off)
      float dx = qx - p.x, dy = qy - p.y, dz = qz - p.z;
      dist = ((dx*dx) + (dy*dy)) + (dz*dz);   // match numpy rounding exactly (no fma)
    }
    if (dist < d2){
      bool c1 = dist < d1, c0 = dist < d0;
      d2 = c1 ? d1 : dist;                 i2 = c1 ? i1 : s;
      float nd1 = c1 ? (c0 ? d0 : dist) : d1;
      int   ni1 = c1 ? (c0 ? i0 : s)    : i1;
      d0 = c0 ? dist : d0;                 i0 = c0 ? s : i0;
      d1 = nd1;                            i1 = ni1;
    }
  }
  pd[g][0][q]=d0; pd[g][1][q]=d1; pd[g][2][q]=d2;
  pi[g][0][q]=i0; pi[g][1][q]=i1; pi[g][2][q]=i2;
  __syncthreads();

  if (t < 64){
    float m0=3.4e38f, m1=3.4e38f, m2=3.4e38f;
    int   j0=0, j1=0, j2=0;
    #pragma unroll
    for (int gg = 0; gg < 8; ++gg){
      #pragma unroll
      for (int p = 0; p < 3; ++p){
        float dist = pd[gg][p][t]; int s = pi[gg][p][t];
        if (dist < m2){
          bool c1 = dist < m1, c0 = dist < m0;
          m2 = c1 ? m1 : dist;                 j2 = c1 ? j1 : s;
          float nd1 = c1 ? (c0 ? m0 : dist) : m1;
          int   ni1 = c1 ? (c0 ? j0 : s)    : j1;
          m0 = c0 ? dist : m0;                 j0 = c0 ? s : j0;
          m1 = nd1;                            j1 = ni1;
        }
      }
    }
    float r0 = 1.f/(m0 + 1e-8f), r1 = 1.f/(m1 + 1e-8f), r2 = 1.f/(m2 + 1e-8f);
    float rs = (r0 + r1) + r2;
    swts[0][t] = r0/rs; swts[1][t] = r1/rs; swts[2][t] = r2/rs;
    sidx[0][t] = j0;    sidx[1][t] = j1;    sidx[2][t] = j2;
  }
  __syncthreads();

  int w = t >> 6, lane = t & 63;
  for (int qq = w*8; qq < w*8 + 8; ++qq){
    float wa = swts[0][qq], wb = swts[1][qq], wc = swts[2][qq];
    int   j0 = sidx[0][qq], j1 = sidx[1][qq], j2 = sidx[2][qq];
    const ushort4 u0 = *(const ushort4*)(p2t + (((size_t)b*SPTS + j0)<<8) + (lane<<2));
    const ushort4 u1 = *(const ushort4*)(p2t + (((size_t)b*SPTS + j1)<<8) + (lane<<2));
    const ushort4 u2 = *(const ushort4*)(p2t + (((size_t)b*SPTS + j2)<<8) + (lane<<2));
    ushort4 ov;
    ov.x = f2bf(wa*bf2f(u0.x) + wb*bf2f(u1.x) + wc*bf2f(u2.x));
    ov.y = f2bf(wa*bf2f(u0.y) + wb*bf2f(u1.y) + wc*bf2f(u2.y));
    ov.z = f2bf(wa*bf2f(u0.z) + wb*bf2f(u1.z) + wc*bf2f(u2.z));
    ov.w = f2bf(wa*bf2f(u0.w) + wb*bf2f(u1.w) + wc*bf2f(u2.w));
    *(ushort4*)(X + ((size_t)b*NPTS + n0 + qq)*384 + 128 + (lane<<2)) = ov;
  }
}

// ======== GEMM v2: BM=64, BN=128, BK=64; swizzled LDS (kb ^= (row&7)<<4); atomic-free stats ========
// C[m][n] = sum_k A[m][k]*Bw[n][k]. 256 thr = 4 waves (wm = wid>>1 in {0,1}, wn = wid&1).
// Per wave: 32x64 output = acc[2][4]. Partial stats -> psum/psq[channel*1024 + rowTile].

__global__ __launch_bounds__(256) void gemm1_k(const u16* __restrict__ A, const u16* __restrict__ Bw,
                                               u16* __restrict__ Cc,
                                               float* __restrict__ psum, float* __restrict__ psq){
  const int K = 384, Nn = 256;
  __shared__ u16 lA[64*64];    // [64 rows][64 k] swizzled, 8KB
  __shared__ u16 lB[128*64];   // 16KB
  __shared__ float sums[128], sqs[128];
  int t = threadIdx.x, lane = t & 63, wid = t >> 6;
  int rowBase = blockIdx.x << 6, colBase = blockIdx.y << 7;
  int wm = wid >> 1, wn = wid & 1;

  const char* pA[2]; char* dA[2];
  #pragma unroll
  for (int j = 0; j < 2; ++j){
    int L = j*4096 + wid*1024 + lane*16;
    int row = L >> 7, kb = L & 127;
    int kbs = kb ^ ((row & 7) << 4);            // pre-swizzled global source
    pA[j] = (const char*)A + ((size_t)(rowBase + row)*K)*2 + kbs;
    dA[j] = (char*)lA + j*4096 + wid*1024;      // wave-uniform dest (HW adds lane*16)
  }
  const char* pB[4]; char* dB[4];
  #pragma unroll
  for (int j = 0; j < 4; ++j){
    int L = j*4096 + wid*1024 + lane*16;
    int row = L >> 7, kb = L & 127;
    int kbs = kb ^ ((row & 7) << 4);
    pB[j] = (const char*)Bw + ((size_t)(colBase + row)*K)*2 + kbs;
    dB[j] = (char*)lB + j*4096 + wid*1024;
  }

  f32x4 z = {0.f,0.f,0.f,0.f};
  f32x4 acc[2][4];
  #pragma unroll
  for (int m = 0; m < 2; ++m)
    #pragma unroll
    for (int n = 0; n < 4; ++n) acc[m][n] = z;

  for (int kk = 0; kk < K; kk += 64){
    size_t ko = (size_t)kk * 2;
    #pragma unroll
    for (int j = 0; j < 2; ++j)
      __builtin_amdgcn_global_load_lds((const __attribute__((address_space(1))) void*)(pA[j] + ko),
                                       (__attribute__((address_space(3))) void*)dA[j], 16, 0, 0);
    #pragma unroll
    for (int j = 0; j < 4; ++j)
      __builtin_amdgcn_global_load_lds((const __attribute__((address_space(1))) void*)(pB[j] + ko),
                                       (__attribute__((address_space(3))) void*)dB[j], 16, 0, 0);
    __syncthreads();
    bf16x8 af[2][2], bfv[4][2];
    #pragma unroll
    for (int m = 0; m < 2; ++m){
      int row = wm*32 + m*16 + (lane & 15);
      int sw = (row & 7) << 4;
      #pragma unroll
      for (int ks = 0; ks < 2; ++ks){
        int kb = (ks*64 + ((lane >> 4) << 4)) ^ sw;
        af[m][ks] = *(const bf16x8*)((const char*)lA + row*128 + kb);
      }
    }
    #pragma unroll
    for (int n = 0; n < 4; ++n){
      int row = wn*64 + n*16 + (lane & 15);
      int sw = (row & 7) << 4;
      #pragma unroll
      for (int ks = 0; ks < 2; ++ks){
        int kb = (ks*64 + ((lane >> 4) << 4)) ^ sw;
        bfv[n][ks] = *(const bf16x8*)((const char*)lB + row*128 + kb);
      }
    }
    #pragma unroll
    for (int ks = 0; ks < 2; ++ks)
      #pragma unroll
      for (int m = 0; m < 2; ++m)
        #pragma unroll
        for (int n = 0; n < 4; ++n)
          acc[m][n] = __builtin_amdgcn_mfma_f32_16x16x32_bf16(af[m][ks], bfv[n][ks], acc[m][n], 0, 0, 0);
    __syncthreads();
  }

  if (t < 128){ sums[t] = 0.f; sqs[t] = 0.f; }
  __syncthreads();
  int colb = colBase + wn*64 + (lane & 15);
  int rowb = rowBase + wm*32 + ((lane >> 4) << 2);
  #pragma unroll
  for (int n = 0; n < 4; ++n){
    float s = 0.f, qq2 = 0.f;
    #pragma unroll
    for (int m = 0; m < 2; ++m){
      #pragma unroll
      for (int r = 0; r < 4; ++r){
        float v = acc[m][n][r];
        Cc[(size_t)(rowb + m*16 + r)*Nn + colb + n*16] = f2bf(v);
        s += v; qq2 += v*v;
      }
    }
    atomicAdd(&sums[wn*64 + n*16 + (lane & 15)], s);
    atomicAdd(&sqs [wn*64 + n*16 + (lane & 15)], qq2);
  }
  __syncthreads();
  if (t < 128){
    int c = colBase + t;
    psum[(size_t)c*1024 + blockIdx.x] = sums[t];
    psq [(size_t)c*1024 + blockIdx.x] = sqs[t];
  }
}

// GEMM2: K=256, Nn=128; A = Y1 with fused BN1+relu applied during reg-staging.
__global__ __launch_bounds__(256) void gemm2_k(const u16* __restrict__ A, const u16* __restrict__ Bw,
                                               u16* __restrict__ Cc,
                                               const float* __restrict__ sc, const float* __restrict__ sh,
                                               float* __restrict__ psum, float* __restrict__ psq){
  const int K = 256, Nn = 128;
  __shared__ u16 lA[64*64];
  __shared__ u16 lB[128*64];
  __shared__ float sums[128], sqs[128];
  int t = threadIdx.x, lane = t & 63, wid = t >> 6;
  int rowBase = blockIdx.x << 6;
  int wm = wid >> 1, wn = wid & 1;

  const char* pB[4]; char* dB[4];
  #pragma unroll
  for (int j = 0; j < 4; ++j){
    int L = j*4096 + wid*1024 + lane*16;
    int row = L >> 7, kb = L & 127;
    int kbs = kb ^ ((row & 7) << 4);
    pB[j] = (const char*)Bw + ((size_t)row*K)*2 + kbs;
    dB[j] = (char*)lB + j*4096 + wid*1024;
  }
  // A reg-staging geometry: thread -> row = t&63, chunk = t>>6 (16 elems = 32B)
  int arow = t & 63, achunk = t >> 6;
  const u16* pArow = A + (size_t)(rowBase + arow)*K + achunk*16;
  int asw = (arow & 7) << 4;
  char* wA0 = (char*)lA + arow*128 + (((achunk*32)      ) ^ asw);
  char* wA1 = (char*)lA + arow*128 + (((achunk*32) + 16 ) ^ asw);

  f32x4 z = {0.f,0.f,0.f,0.f};
  f32x4 acc[2][4];
  #pragma unroll
  for (int m = 0; m < 2; ++m)
    #pragma unroll
    for (int n = 0; n < 4; ++n) acc[m][n] = z;

  for (int kk = 0; kk < K; kk += 64){
    size_t ko = (size_t)kk * 2;
    #pragma unroll
    for (int j = 0; j < 4; ++j)
      __builtin_amdgcn_global_load_lds((const __attribute__((address_space(1))) void*)(pB[j] + ko),
                                       (__attribute__((address_space(3))) void*)dB[j], 16, 0, 0);
    // A: load 16 bf16, apply BN1+relu (identical math to previous bnrelu_k), ds_write swizzled
    u16x8 y0 = *(const u16x8*)(pArow + kk);
    u16x8 y1 = *(const u16x8*)(pArow + kk + 8);
    int k0 = kk + achunk*16;                    // wave-uniform
    bf16x8 o0, o1;
    #pragma unroll
    for (int j = 0; j < 8; ++j){
      float v = bf2f((u16)y0[j]) * sc[k0 + j] + sh[k0 + j];
      o0[j] = (short)f2bf(fmaxf(v, 0.f));
    }
    #pragma unroll
    for (int j = 0; j < 8; ++j){
      float v = bf2f((u16)y1[j]) * sc[k0 + 8 + j] + sh[k0 + 8 + j];
      o1[j] = (short)f2bf(fmaxf(v, 0.f));
    }
    *(bf16x8*)wA0 = o0;
    *(bf16x8*)wA1 = o1;
    __syncthreads();
    bf16x8 af[2][2], bfv[4][2];
    #pragma unroll
    for (int m = 0; m < 2; ++m){
      int row = wm*32 + m*16 + (lane & 15);
      int sw = (row & 7) << 4;
      #pragma unroll
      for (int ks = 0; ks < 2; ++ks){
        int kb = (ks*64 + ((lane >> 4) << 4)) ^ sw;
        af[m][ks] = *(const bf16x8*)((const char*)lA + row*128 + kb);
      }
    }
    #pragma unroll
    for (int n = 0; n < 4; ++n){
      int row = wn*64 + n*16 + (lane & 15);
      int sw = (row & 7) << 4;
      #pragma unroll
      for (int ks = 0; ks < 2; ++ks){
        int kb = (ks*64 + ((lane >> 4) << 4)) ^ sw;
        bfv[n][ks] = *(const bf16x8*)((const char*)lB + row*128 + kb);
      }
    }
    #pragma unroll
    for (int ks = 0; ks < 2; ++ks)
      #pragma unroll
      for (int m = 0; m < 2; ++m)
        #pragma unroll
        for (int n = 0; n < 4; ++n)
          acc[m][n] = __builtin_amdgcn_mfma_f32_16x16x32_bf16(af[m][ks], bfv[n][ks], acc[m][n], 0, 0, 0);
    __syncthreads();
  }

  if (t < 128){ sums[t] = 0.f; sqs[t] = 0.f; }
  __syncthreads();
  int colb = wn*64 + (lane & 15);
  int rowb = rowBase + wm*32 + ((lane >> 4) << 2);
  #pragma unroll
  for (int n = 0; n < 4; ++n){
    float s = 0.f, qq2 = 0.f;
    #pragma unroll
    for (int m = 0; m < 2; ++m){
      #pragma unroll
      for (int r = 0; r < 4; ++r){
        float v = acc[m][n][r];
        Cc[(size_t)(rowb + m*16 + r)*Nn + colb + n*16] = f2bf(v);
        s += v; qq2 += v*v;
      }
    }
    atomicAdd(&sums[colb + n*16], s);
    atomicAdd(&sqs [colb + n*16], qq2);
  }
  __syncthreads();
  if (t < 128){
    psum[(size_t)t*1024 + blockIdx.x] = sums[t];
    psq [(size_t)t*1024 + blockIdx.x] = sqs[t];
  }
}

// ---------------- reduce partials -> per-channel BN scale/shift (bias cancels in BN) ----------------
__global__ __launch_bounds__(256) void finalize2_k(const float* __restrict__ psum, const float* __restrict__ psq,
                                                   const float* __restrict__ g, const float* __restrict__ bet,
                                                   float* __restrict__ sc, float* __restrict__ sh){
  __shared__ float rs[256], rq[256];
  int c = blockIdx.x, t = threadIdx.x;
  float s = 0.f, q = 0.f;
  for (int rt = t; rt < 1024; rt += 256){
    s += psum[(size_t)c*1024 + rt];
    q += psq [(size_t)c*1024 + rt];
  }
  rs[t] = s; rq[t] = q;
  __syncthreads();
  for (int off = 128; off; off >>= 1){
    if (t < off){ rs[t] += rs[t+off]; rq[t] += rq[t+off]; }
    __syncthreads();
  }
  if (t == 0){
    const float inv = 1.f/65536.f;
    float mean = rs[0]*inv;
    float var  = rq[0]*inv - mean*mean;
    float rstd = rsqrtf(var + 1e-5f);
    float scl  = g[c]*rstd;
    sc[c] = scl;
    sh[c] = bet[c] - mean*scl;
  }
}

// ---------------- BN2 + relu + transpose (BN,128) -> (B,128,N) fp32 out ----------------
__global__ __launch_bounds__(256) void finalout_k(const u16* __restrict__ y2, const float* __restrict__ sc,
                                                  const float* __restrict__ sh, float* __restrict__ out){
  __shared__ float tl[128][65];
  int t  = threadIdx.x;
  int b  = blockIdx.x >> 6;
  int n0 = (blockIdx.x & 63) << 6;
  for (int i = t; i < 8192; i += 256){
    int r = i >> 7, c = i & 127;
    float v = bf2f(y2[((size_t)b*NPTS + n0 + r)*128 + c]);
    v = fmaxf(v*sc[c] + sh[c], 0.f);
    tl[c][r] = v;
  }
  __syncthreads();
  for (int i = t; i < 8192; i += 256){
    int o = i >> 6, j = i & 63;
    out[(size_t)b*128*NPTS + (size_t)o*NPTS + n0 + j] = tl[o][j];
  }
}

extern "C" void kernel_launch(void* const* d_in, const int* in_sizes, int n_in,
                              void* d_out, int out_size, void* d_ws, size_t ws_size,
                              hipStream_t stream) {
  const float* xyz1    = (const float*)d_in[0];
  const float* xyz2    = (const float*)d_in[1];
  const float* points1 = (const float*)d_in[2];
  const float* points2 = (const float*)d_in[3];
  const float* w1      = (const float*)d_in[4];
  // d_in[5] = b1 (cancels in BN)
  const float* g1      = (const float*)d_in[6];
  const float* beta1   = (const float*)d_in[7];
  const float* w2      = (const float*)d_in[8];
  // d_in[9] = b2 (cancels in BN)
  const float* g2      = (const float*)d_in[10];
  const float* beta2   = (const float*)d_in[11];

  char* ws = (char*)d_ws;
  // layout (bytes):
  u16*  X    = (u16*)ws;                          // BN x 384 bf16 = 50,331,648   (dead after gemm1)
  u16*  Y2   = (u16*)ws;                          // alias X: BN x 128 bf16 = 16,777,216
  u16*  Y1   = (u16*)(ws + 50331648);             // BN x 256 bf16 = 33,554,432
  u16*  p2t  = (u16*)(ws + 83886080);             // B x S x 256 bf16 = 8,388,608 (dead after knn)
  u16*  w1b  = (u16*)(ws + 92274688);             // 196,608
  u16*  w2b  = (u16*)(ws + 92471296);             // 65,536
  // partials/stats alias p2t's region (p2t dead once knn completes; stream order guarantees safety)
  float* psum1 = (float*)(ws + 83886080);         // 256*1024*4 = 1MB
  float* psq1  = (float*)(ws + 84934656);         // 1MB
  float* psum2 = (float*)(ws + 85983232);         // 128*1024*4 = 512KB
  float* psq2  = (float*)(ws + 86507520);         // 512KB
  float* sc1   = (float*)(ws + 87031808);
  float* sh1   = (float*)(ws + 87032832);
  float* sc2   = (float*)(ws + 87033856);
  float* sh2   = (float*)(ws + 87034368);

  convw_k<<<512, 256, 0, stream>>>(w1, w2, w1b, w2b);
  transpose_k<<<dim3(64, 16), 256, 0, stream>>>(points1, X,   128, NPTS, 384);
  transpose_k<<<dim3(16, 16), 256, 0, stream>>>(points2, p2t, 256, SPTS, 256);
  knn_k<<<1024, 512, 0, stream>>>(xyz1, xyz2, p2t, X);
  gemm1_k<<<dim3(1024, 2), 256, 0, stream>>>(X, w1b, Y1, psum1, psq1);
  finalize2_k<<<256, 256, 0, stream>>>(psum1, psq1, g1, beta1, sc1, sh1);
  gemm2_k<<<1024, 256, 0, stream>>>(Y1, w2b, Y2, sc1, sh1, psum2, psq2);
  finalize2_k<<<128, 256, 0, stream>>>(psum2, psq2, g2, beta2, sc2, sh2);
  finalout_k<<<1024, 256, 0, stream>>>(Y2, sc2, sh2, (float*)d_out);
}